// Round 2
// baseline (742.124 us; speedup 1.0000x reference)
//
#include <hip/hip_runtime.h>

#define VC 1600
#define EPSF 1e-5f

// ws layout (float offsets)
#define WS_MASKJ  0
#define WS_WPACK  1600
#define WS_DWPACK 5696
#define WS_ABY    9792
#define WS_ABR    16192
#define WS_COLSUM 16448
#define WS_QYP    18048
#define QYP_STRIDE 3328
// big-ws path regions
#define WS_ABY2   1721984          // float offset; 3200 float2 (dest-indexed coeffs)
#define WS_Y_SH   3456768          // SHORT offset: y bf16 [n][v][d]
#define WS_R_SH   55885568         // SHORT offset: res bf16 [n][v][d]
#define WS_NEED_BYTES 216628736ULL

typedef __attribute__((ext_vector_type(8))) short s16x8;
typedef __attribute__((ext_vector_type(4))) short s16x4;
typedef __attribute__((ext_vector_type(4))) float f32x4;

__device__ __forceinline__ short f2bf(float f) {
  unsigned u = __builtin_bit_cast(unsigned, f);
  u += 0x7fffu + ((u >> 16) & 1u);
  return (short)(u >> 16);
}
__device__ __forceinline__ float bf2f(short s) {
  unsigned u = ((unsigned)(unsigned short)s) << 16;
  return __builtin_bit_cast(float, u);
}

// stage one float4: raw (contiguous) + masked scatter to gathered position.
__device__ __forceinline__ void stage_elem(int j, int base, int vstr, float4 xv,
                                           const float* mj, short* s_raw, short* s_xm) {
  int u = j >> 6, c = j & 63;
  s16x4 pk; pk[0]=f2bf(xv.x); pk[1]=f2bf(xv.y); pk[2]=f2bf(xv.z); pk[3]=f2bf(xv.w);
  *(s16x4*)(s_raw + (base + u*vstr)*72 + c) = pk;
  int v0 = (u - c + 75) % 25;
  float xa[4] = {xv.x, xv.y, xv.z, xv.w};
#pragma unroll
  for (int e = 0; e < 4; e++) {
    int ve = v0 - e; if (ve < 0) ve += 25;
    s_xm[(base + ve*vstr)*72 + c + e] = f2bf(xa[e] * mj[e]);
  }
}

// ---------------- init ----------------
__global__ void k_init(const float* __restrict__ fm, const float* __restrict__ W,
                       const float* __restrict__ dw, float* __restrict__ ws) {
  int g = blockIdx.x * 256 + threadIdx.x;
  if (g < VC) {
    int c = g & 63, jv = g >> 6;
    int v = (jv - c + 75) % 25;
    ws[WS_MASKJ + g] = tanhf(fm[v * 64 + c]) + 1.0f;
    ws[WS_COLSUM + g] = 0.0f;
  }
  if (g >= 2048 && g < 3072) {
    int idx = g - 2048;
    int frag = idx >> 6, lane = idx & 63;
    int nt = frag >> 1, k = frag & 1, q = lane >> 4, l = lane & 15;
    s16x8 pk;
#pragma unroll
    for (int j = 0; j < 8; j++) {
      int c = k * 32 + q * 8 + j;
      pk[j] = f2bf(W[c * 128 + nt * 16 + l]);
    }
    ((s16x8*)(ws + WS_WPACK))[idx] = pk;
  }
  if (g >= 3072 && g < 4096) {
    int idx = g - 3072;
    int frag = idx >> 6, lane = idx & 63;
    int nt = frag >> 1, k = frag & 1, q = lane >> 4, l = lane & 15;
    s16x8 pk;
#pragma unroll
    for (int j = 0; j < 8; j++) {
      int c = k * 32 + q * 8 + j;
      pk[j] = f2bf(dw[(nt * 16 + l) * 64 + c]);
    }
    ((s16x8*)(ws + WS_DWPACK))[idx] = pk;
  }
}

// ---------------- pass 1: stats in regs + store y/res bf16 [n][v][d] ----------------
// 4-row chunks (vstr=4): slot = r + v*4, 100 slots + 12 pad -> 7 MFMA tiles of 16.
// Unique q ownership: v = vp*4 + quad, d = (nt0+a)*16 + l15 -> no LDS stats, no atomics.
__launch_bounds__(256, 4)
__global__ void k_stats(const float* __restrict__ x0, float* __restrict__ ws, int do_store) {
  __shared__ short s_raw[8064];   // 112 slots x 72
  __shared__ short s_xm[8064];
  int tid = threadIdx.x;
  int wave = tid >> 6, lane = tid & 63, quad = lane >> 4, l15 = lane & 15;
  for (int t = tid; t < 864; t += 256) { s_raw[7200 + t] = 0; s_xm[7200 + t] = 0; }
  const s16x8* wpack = (const s16x8*)(ws + WS_WPACK);
  const s16x8* dwpack = (const s16x8*)(ws + WS_DWPACK);
  short* wsy = (short*)ws + WS_Y_SH;
  short* wsr = (short*)ws + WS_R_SH;

  int nt0 = wave * 2;
  s16x8 bw[2][2], bd[2][2];
#pragma unroll
  for (int a = 0; a < 2; a++) {
    int nt = nt0 + a;
    bw[a][0] = wpack[(nt * 2 + 0) * 64 + lane];
    bw[a][1] = wpack[(nt * 2 + 1) * 64 + lane];
    bd[a][0] = dwpack[(nt * 2 + 0) * 64 + lane];
    bd[a][1] = dwpack[(nt * 2 + 1) * 64 + lane];
  }
  float mj0[4], mj1[4];
  {
    float4 m4 = *(const float4*)(ws + WS_MASKJ + tid * 4);
    mj0[0]=m4.x; mj0[1]=m4.y; mj0[2]=m4.z; mj0[3]=m4.w;
  }
  if (tid < 144) {
    float4 m4 = *(const float4*)(ws + WS_MASKJ + 1024 + tid * 4);
    mj1[0]=m4.x; mj1[1]=m4.y; mj1[2]=m4.z; mj1[3]=m4.w;
  }
  float cs[8] = {0,0,0,0,0,0,0,0};
  float rq0 = 0.f, rq1 = 0.f;
  float qy[7][2];
#pragma unroll
  for (int i = 0; i < 7; i++) { qy[i][0] = 0.f; qy[i][1] = 0.f; }

  for (int chunk = 0; chunk < 8; chunk++) {
    int n0 = blockIdx.x * 32 + chunk * 4;
    __syncthreads();
    for (int r = 0; r < 4; r++) {
      const float* rowp = x0 + (size_t)(n0 + r) * VC;
      float4 xv = *(const float4*)(rowp + tid * 4);
      cs[0]+=xv.x; cs[1]+=xv.y; cs[2]+=xv.z; cs[3]+=xv.w;
      stage_elem(tid * 4, r, 4, xv, mj0, s_raw, s_xm);
      if (tid < 144) {
        float4 xw = *(const float4*)(rowp + 1024 + tid * 4);
        cs[4]+=xw.x; cs[5]+=xw.y; cs[6]+=xw.z; cs[7]+=xw.w;
        stage_elem(1024 + tid * 4, r, 4, xw, mj1, s_raw, s_xm);
      }
    }
    __syncthreads();
#pragma unroll
    for (int vp = 0; vp < 7; vp++) {
      int rb = vp * 16;
      const short* px = s_xm + (rb + l15) * 72 + quad * 8;
      const short* pr = s_raw + (rb + l15) * 72 + quad * 8;
      s16x8 a0 = *(const s16x8*)px;
      s16x8 a1 = *(const s16x8*)(px + 32);
      s16x8 r0 = *(const s16x8*)pr;
      s16x8 r1 = *(const s16x8*)(pr + 32);
#pragma unroll
      for (int a = 0; a < 2; a++) {
        f32x4 acc = {0.f, 0.f, 0.f, 0.f};
        acc = __builtin_amdgcn_mfma_f32_16x16x32_bf16(a0, bw[a][0], acc, 0, 0, 0);
        acc = __builtin_amdgcn_mfma_f32_16x16x32_bf16(a1, bw[a][1], acc, 0, 0, 0);
        qy[vp][a] += acc[0]*acc[0] + acc[1]*acc[1] + acc[2]*acc[2] + acc[3]*acc[3];
        f32x4 rc = {0.f, 0.f, 0.f, 0.f};
        rc = __builtin_amdgcn_mfma_f32_16x16x32_bf16(r0, bd[a][0], rc, 0, 0, 0);
        rc = __builtin_amdgcn_mfma_f32_16x16x32_bf16(r1, bd[a][1], rc, 0, 0, 0);
        float t2 = rc[0]*rc[0] + rc[1]*rc[1] + rc[2]*rc[2] + rc[3]*rc[3];
        if (a == 0) rq0 += t2; else rq1 += t2;
      }
      // transposed MFMAs (swap A/B): lane holds 4 consecutive d for one slot.
      if (do_store) {
        int slot = rb + l15;
        int vv2 = slot >> 2, rr2 = slot & 3;
        size_t bsh = (size_t)((n0 + rr2) * 25 + vv2) * 128 + nt0 * 16 + quad * 4;
#pragma unroll
        for (int aa = 0; aa < 2; aa++) {
          f32x4 tY = {0.f, 0.f, 0.f, 0.f};
          tY = __builtin_amdgcn_mfma_f32_16x16x32_bf16(bw[aa][0], a0, tY, 0, 0, 0);
          tY = __builtin_amdgcn_mfma_f32_16x16x32_bf16(bw[aa][1], a1, tY, 0, 0, 0);
          f32x4 tR = {0.f, 0.f, 0.f, 0.f};
          tR = __builtin_amdgcn_mfma_f32_16x16x32_bf16(bd[aa][0], r0, tR, 0, 0, 0);
          tR = __builtin_amdgcn_mfma_f32_16x16x32_bf16(bd[aa][1], r1, tR, 0, 0, 0);
          if (vv2 < 25) {
            s16x4 ky, kr;
#pragma unroll
            for (int e = 0; e < 4; e++) { ky[e] = f2bf(tY[e]); kr[e] = f2bf(tR[e]); }
            *(s16x4*)(wsy + bsh + aa * 16) = ky;
            *(s16x4*)(wsr + bsh + aa * 16) = kr;
          }
        }
      }
    }
  }
  // write partials straight from registers
  float* qp = ws + WS_QYP + (size_t)blockIdx.x * QYP_STRIDE;
  rq0 += __shfl_xor(rq0, 16); rq0 += __shfl_xor(rq0, 32);
  rq1 += __shfl_xor(rq1, 16); rq1 += __shfl_xor(rq1, 32);
  if (quad == 0) {
    qp[3200 + nt0 * 16 + l15] = rq0;
    qp[3200 + (nt0 + 1) * 16 + l15] = rq1;
  }
#pragma unroll
  for (int vp = 0; vp < 7; vp++) {
    int vq = vp * 4 + quad;
    if (vq < 25) {
      qp[vq * 128 + nt0 * 16 + l15] = qy[vp][0];
      qp[vq * 128 + (nt0 + 1) * 16 + l15] = qy[vp][1];
    }
  }
#pragma unroll
  for (int e = 0; e < 4; e++) atomicAdd(ws + WS_COLSUM + tid * 4 + e, cs[e]);
  if (tid < 144) {
#pragma unroll
    for (int e = 0; e < 4; e++) atomicAdd(ws + WS_COLSUM + 1024 + tid * 4 + e, cs[4 + e]);
  }
}

// ---------------- reduce ----------------
__global__ void k_reduce(const float* __restrict__ gamma, const float* __restrict__ beta,
                         const float* __restrict__ dgamma, const float* __restrict__ dbeta,
                         const float* __restrict__ W, const float* __restrict__ dw,
                         float* __restrict__ ws, int do_store) {
  int tid = threadIdx.x;
  if (blockIdx.x == 25) {
    __shared__ float s_cs[64];
    if (tid < 64) {
      float s = 0.f;
#pragma unroll
      for (int v = 0; v < 25; v++) s += ws[WS_COLSUM + v * 64 + tid];
      s_cs[tid] = s;
    }
    __syncthreads();
    int d = tid;
    float q = 0.f;
#pragma unroll 8
    for (int b2 = 0; b2 < 512; b2++) q += ws[WS_QYP + (size_t)b2 * QYP_STRIDE + 3200 + d];
    float m = 0.f;
#pragma unroll 8
    for (int c = 0; c < 64; c++) m += s_cs[c] * dw[d * 64 + c];
    m *= (1.0f / 409600.0f);
    float var = q * (1.0f / 409600.0f) - m * m;
    float a = dgamma[d] * rsqrtf(var + EPSF);
    ((float2*)(ws + WS_ABR))[d] = make_float2(a, dbeta[d] - m * a);
    return;
  }
  __shared__ float s_cm[1600];
  for (int t = tid; t < 1600; t += 128)
    s_cm[t] = ws[WS_COLSUM + t] * ws[WS_MASKJ + t];
  __syncthreads();
  int f = blockIdx.x * 128 + tid;
  int v = f >> 7, d = f & 127;
  float q = 0.f;
#pragma unroll 8
  for (int b2 = 0; b2 < 512; b2++) q += ws[WS_QYP + (size_t)b2 * QYP_STRIDE + f];
  float m = 0.f;
  int p = v * 64;
#pragma unroll 8
  for (int c = 0; c < 64; c++) {
    m += s_cm[p] * W[c * 128 + d];
    p += 65; if (p >= VC) p -= VC;
  }
  m *= (1.0f / 16384.0f);
  float var = q * (1.0f / 16384.0f) - m * m;
  int d25 = d % 25;
  int vo = v + d25; if (vo >= 25) vo -= 25;
  int jg = vo * 128 + d;
  float a = gamma[jg] * rsqrtf(var + EPSF);
  float bb = beta[jg] - m * a;
  ((float2*)(ws + WS_ABY))[f] = make_float2(a, bb);
  if (do_store) ((float2*)(ws + WS_ABY2))[vo * 128 + d] = make_float2(a, bb);
}

// ---------------- pass 2: streaming transpose, 2 rows/block, 6 blocks/CU ----------------
__launch_bounds__(256, 6)
__global__ void k_out(const float* __restrict__ ws, float* __restrict__ out) {
  __shared__ short s_y[6400];
  __shared__ short s_r[6400];
  int tid = threadIdx.x;
  int n0 = blockIdx.x * 2;
  const short* wsy = (const short*)ws + WS_Y_SH + (size_t)n0 * 3200;
  const short* wsr = (const short*)ws + WS_R_SH + (size_t)n0 * 3200;
  for (int idx = tid; idx < 800; idx += 256) {
    int tl = idx / 400;
    int rem = idx - tl * 400;
    int v = rem >> 4, dblk = rem & 15;
    int phys = (((tl * 25 + v) << 4) + (dblk ^ (v & 15))) * 8;
    *(s16x8*)(s_y + phys) = *(const s16x8*)(wsy + idx * 8);
    *(s16x8*)(s_r + phys) = *(const s16x8*)(wsr + idx * 8);
  }
  __syncthreads();
  int b = n0 >> 9, t0 = n0 & 511;
  float* ob = out + (size_t)b * 1638400 + (size_t)t0 * 25;
  const float2* aby2 = (const float2*)(ws + WS_ABY2);
  const float2* abrp = (const float2*)(ws + WS_ABR);
  for (int u = tid; u < 3200; u += 256) {
    int dd = u / 25;
    int rem = u - dd * 25;
    int q0 = rem * 2;            // 0..48, even; q-range [0,50) spans 2 t-rows
    int d25 = dd % 25;
    float2 ar = abrp[dd];
    int tl = (q0 >= 25) ? 1 : 0;
    int vo = q0 - tl * 25;
    int sh = dd >> 3, dlo = dd & 7;
    float ov[2];
#pragma unroll
    for (int e = 0; e < 2; e++) {
      int vi = vo - d25; if (vi < 0) vi += 25;
      int ady = (((tl * 25 + vi) << 4) + (sh ^ (vi & 15))) * 8 + dlo;   // y is shift-scattered
      int adr = (((tl * 25 + vo) << 4) + (sh ^ (vo & 15))) * 8 + dlo;   // res is not
      float yv = bf2f(s_y[ady]);
      float rv = bf2f(s_r[adr]);
      float2 ay = aby2[vo * 128 + dd];
      ov[e] = fmaxf(yv * ay.x + ay.y + rv * ar.x + ar.y, 0.0f);
      vo++; if (vo == 25) { vo = 0; tl++; }
    }
    float2 o; o.x = ov[0]; o.y = ov[1];
    *(float2*)(ob + (size_t)dd * 12800 + q0) = o;
  }
}

// ---------------- fallback pass 2 (small ws): original recompute kernel ----------------
__launch_bounds__(256, 2)
__global__ void k_main(const float* __restrict__ x0, const float* __restrict__ ws,
                       float* __restrict__ out) {
  __shared__ short s_raw[112 * 72];
  __shared__ short s_xm[112 * 72];
  __shared__ short s_ybuf[100 * 129];
  int tid = threadIdx.x;
  int wave = tid >> 6, lane = tid & 63, quad = lane >> 4, l15 = lane & 15;
  int n0 = blockIdx.x * 4;
  for (int t = tid; t < 1600; t += 256) {
    int flat = t * 4;
    int nl = flat / VC;
    int j = flat - nl * VC;
    float4 xv = *(const float4*)(x0 + (size_t)n0 * VC + flat);
    float4 m4 = *(const float4*)(ws + WS_MASKJ + j);
    float mj[4] = {m4.x, m4.y, m4.z, m4.w};
    stage_elem(j, nl * 25, 1, xv, mj, (short*)s_raw, (short*)s_xm);
  }
  __syncthreads();
  const s16x8* wpack = (const s16x8*)(ws + WS_WPACK);
  const float2* aby = (const float2*)(ws + WS_ABY);
  {
    s16x8 b0, b1;
#pragma unroll
    for (int ji = 0; ji < 14; ji++) {
      int job = wave * 14 + ji;
      int nt = job / 7, mt = job - nt * 7;
      if (ji == 0 || ji == 7) {
        b0 = wpack[(nt * 2 + 0) * 64 + lane];
        b1 = wpack[(nt * 2 + 1) * 64 + lane];
      }
      int mbase = mt * 16;
      const short* pa = s_xm + (mbase + l15) * 72 + quad * 8;
      s16x8 a0 = *(const s16x8*)(pa);
      s16x8 a1 = *(const s16x8*)(pa + 32);
      f32x4 acc = {0.f, 0.f, 0.f, 0.f};
      acc = __builtin_amdgcn_mfma_f32_16x16x32_bf16(a0, b0, acc, 0, 0, 0);
      acc = __builtin_amdgcn_mfma_f32_16x16x32_bf16(a1, b1, acc, 0, 0, 0);
      int d = nt * 16 + l15;
      int d25 = d % 25;
#pragma unroll
      for (int i = 0; i < 4; i++) {
        int s = mbase + quad * 4 + i;
        if (s < 100) {
          int r = s / 25;
          int vv = s - r * 25;
          float2 ab = aby[vv * 128 + d];
          float val = acc[i] * ab.x + ab.y;
          int vo = vv + d25; if (vo >= 25) vo -= 25;
          s_ybuf[(r * 25 + vo) * 129 + d] = f2bf(val);
        }
      }
    }
  }
  __syncthreads();
  const s16x8* dwpack = (const s16x8*)(ws + WS_DWPACK);
  const float2* abr = (const float2*)(ws + WS_ABR);
  {
    s16x8 b0, b1; float2 ab = make_float2(0.f, 0.f);
#pragma unroll
    for (int ji = 0; ji < 14; ji++) {
      int job = wave * 14 + ji;
      int nt = job / 7, mt = job - nt * 7;
      if (ji == 0 || ji == 7) {
        b0 = dwpack[(nt * 2 + 0) * 64 + lane];
        b1 = dwpack[(nt * 2 + 1) * 64 + lane];
        ab = abr[nt * 16 + l15];
      }
      int mbase = mt * 16;
      const short* pa = s_raw + (mbase + l15) * 72 + quad * 8;
      s16x8 a0 = *(const s16x8*)(pa);
      s16x8 a1 = *(const s16x8*)(pa + 32);
      f32x4 acc = {0.f, 0.f, 0.f, 0.f};
      acc = __builtin_amdgcn_mfma_f32_16x16x32_bf16(a0, b0, acc, 0, 0, 0);
      acc = __builtin_amdgcn_mfma_f32_16x16x32_bf16(a1, b1, acc, 0, 0, 0);
      int d = nt * 16 + l15;
#pragma unroll
      for (int i = 0; i < 4; i++) {
        int s = mbase + quad * 4 + i;
        if (s < 100) {
          int r = s / 25;
          int vv = s - r * 25;
          int ad = (r * 25 + vv) * 129 + d;
          float val = acc[i] * ab.x + ab.y + bf2f(s_ybuf[ad]);
          val = fmaxf(val, 0.0f);
          s_ybuf[ad] = f2bf(val);
        }
      }
    }
  }
  __syncthreads();
  int b = n0 >> 9, t0 = n0 & 511;
  float* ob = out + (size_t)b * 1638400 + (size_t)t0 * 25;
  for (int it = tid; it < 3200; it += 256) {
    int dd = it / 25;
    int qg = it - dd * 25;
    int q0 = qg * 4;
    float4 o;
    o.x = bf2f(s_ybuf[(q0 + 0) * 129 + dd]);
    o.y = bf2f(s_ybuf[(q0 + 1) * 129 + dd]);
    o.z = bf2f(s_ybuf[(q0 + 2) * 129 + dd]);
    o.w = bf2f(s_ybuf[(q0 + 3) * 129 + dd]);
    *(float4*)(ob + (size_t)dd * 12800 + q0) = o;
  }
}

extern "C" void kernel_launch(void* const* d_in, const int* in_sizes, int n_in,
                              void* d_out, int out_size, void* d_ws, size_t ws_size,
                              hipStream_t stream) {
  const float* x0    = (const float*)d_in[0];
  const float* fm    = (const float*)d_in[1];
  const float* W     = (const float*)d_in[2];
  const float* bn_g  = (const float*)d_in[4];
  const float* bn_b  = (const float*)d_in[5];
  const float* dw    = (const float*)d_in[6];
  const float* dbn_g = (const float*)d_in[8];
  const float* dbn_b = (const float*)d_in[9];
  float* ws = (float*)d_ws;
  float* out = (float*)d_out;
  int big = (ws_size >= WS_NEED_BYTES) ? 1 : 0;
  k_init<<<20, 256, 0, stream>>>(fm, W, dw, ws);
  k_stats<<<512, 256, 0, stream>>>(x0, ws, big);
  k_reduce<<<26, 128, 0, stream>>>(bn_g, bn_b, dbn_g, dbn_b, W, dw, ws, big);
  if (big) k_out<<<8192, 256, 0, stream>>>(ws, out);
  else     k_main<<<4096, 256, 0, stream>>>(x0, ws, out);
}

// Round 3
// 725.399 us; speedup vs baseline: 1.0231x; 1.0231x over previous
//
#include <hip/hip_runtime.h>

#define VC 1600
#define EPSF 1e-5f

// ws layout (float offsets)
#define WS_MASKJ  0
#define WS_WPACK  1600
#define WS_DWPACK 5696
#define WS_ABY    9792
#define WS_ABR    16192
#define WS_COLSUM 16448
#define WS_QYP    18048
#define QYP_STRIDE 3328
// big-ws path regions
#define WS_ABY2   1721984          // float offset; 3200 float2 (dest-indexed coeffs)
#define WS_Y_SH   3456768          // SHORT offset: y bf16 fragment layout, 12800 shorts/chunk
#define WS_R_SH   55885568         // SHORT offset: res bf16 fragment layout
#define WS_NEED_BYTES 216628736ULL

typedef __attribute__((ext_vector_type(8))) short s16x8;
typedef __attribute__((ext_vector_type(4))) short s16x4;
typedef __attribute__((ext_vector_type(4))) float f32x4;

__device__ __forceinline__ short f2bf(float f) {
  unsigned u = __builtin_bit_cast(unsigned, f);
  u += 0x7fffu + ((u >> 16) & 1u);
  return (short)(u >> 16);
}
__device__ __forceinline__ float bf2f(short s) {
  unsigned u = ((unsigned)(unsigned short)s) << 16;
  return __builtin_bit_cast(float, u);
}

// stage one float4: raw (contiguous) + masked scatter to gathered position.
__device__ __forceinline__ void stage_elem(int j, int base, int vstr, float4 xv,
                                           const float* mj, short* s_raw, short* s_xm) {
  int u = j >> 6, c = j & 63;
  s16x4 pk; pk[0]=f2bf(xv.x); pk[1]=f2bf(xv.y); pk[2]=f2bf(xv.z); pk[3]=f2bf(xv.w);
  *(s16x4*)(s_raw + (base + u*vstr)*72 + c) = pk;
  int v0 = (u - c + 75) % 25;
  float xa[4] = {xv.x, xv.y, xv.z, xv.w};
#pragma unroll
  for (int e = 0; e < 4; e++) {
    int ve = v0 - e; if (ve < 0) ve += 25;
    s_xm[(base + ve*vstr)*72 + c + e] = f2bf(xa[e] * mj[e]);
  }
}

// ---------------- init ----------------
__global__ void k_init(const float* __restrict__ fm, const float* __restrict__ W,
                       const float* __restrict__ dw, float* __restrict__ ws) {
  int g = blockIdx.x * 256 + threadIdx.x;
  if (g < VC) {
    int c = g & 63, jv = g >> 6;
    int v = (jv - c + 75) % 25;
    ws[WS_MASKJ + g] = tanhf(fm[v * 64 + c]) + 1.0f;
    ws[WS_COLSUM + g] = 0.0f;
  }
  if (g >= 2048 && g < 3072) {
    int idx = g - 2048;
    int frag = idx >> 6, lane = idx & 63;
    int nt = frag >> 1, k = frag & 1, q = lane >> 4, l = lane & 15;
    s16x8 pk;
#pragma unroll
    for (int j = 0; j < 8; j++) {
      int c = k * 32 + q * 8 + j;
      pk[j] = f2bf(W[c * 128 + nt * 16 + l]);
    }
    ((s16x8*)(ws + WS_WPACK))[idx] = pk;
  }
  if (g >= 3072 && g < 4096) {
    int idx = g - 3072;
    int frag = idx >> 6, lane = idx & 63;
    int nt = frag >> 1, k = frag & 1, q = lane >> 4, l = lane & 15;
    s16x8 pk;
#pragma unroll
    for (int j = 0; j < 8; j++) {
      int c = k * 32 + q * 8 + j;
      pk[j] = f2bf(dw[(nt * 16 + l) * 64 + c]);
    }
    ((s16x8*)(ws + WS_DWPACK))[idx] = pk;
  }
}

// ---------------- pass 1: stats in regs + fragment-layout y/res stores ----------------
// 4-row chunks (vstr=4): slot = r + v*4, 100 slots + 12 pad -> 7 MFMA tiles of 16.
// Fragment store: per (vp, wave, aa): 64 lanes x 8B contiguous = one 512-B line set.
// Chunk region (shorts): vp<6: vp*2048 + wave*512 + aa*256 + lane*4
//                        vp=6 (l15<4 only): 12288 + (wave*2+aa)*64 + (quad*4+l15)*4
__launch_bounds__(256, 4)
__global__ void k_stats(const float* __restrict__ x0, float* __restrict__ ws, int do_store) {
  __shared__ short s_raw[8064];   // 112 slots x 72
  __shared__ short s_xm[8064];
  int tid = threadIdx.x;
  int wave = tid >> 6, lane = tid & 63, quad = lane >> 4, l15 = lane & 15;
  for (int t = tid; t < 864; t += 256) { s_raw[7200 + t] = 0; s_xm[7200 + t] = 0; }
  const s16x8* wpack = (const s16x8*)(ws + WS_WPACK);
  const s16x8* dwpack = (const s16x8*)(ws + WS_DWPACK);
  short* wsy = (short*)ws + WS_Y_SH;
  short* wsr = (short*)ws + WS_R_SH;

  int nt0 = wave * 2;
  s16x8 bw[2][2], bd[2][2];
#pragma unroll
  for (int a = 0; a < 2; a++) {
    int nt = nt0 + a;
    bw[a][0] = wpack[(nt * 2 + 0) * 64 + lane];
    bw[a][1] = wpack[(nt * 2 + 1) * 64 + lane];
    bd[a][0] = dwpack[(nt * 2 + 0) * 64 + lane];
    bd[a][1] = dwpack[(nt * 2 + 1) * 64 + lane];
  }
  float mj0[4], mj1[4];
  {
    float4 m4 = *(const float4*)(ws + WS_MASKJ + tid * 4);
    mj0[0]=m4.x; mj0[1]=m4.y; mj0[2]=m4.z; mj0[3]=m4.w;
  }
  if (tid < 144) {
    float4 m4 = *(const float4*)(ws + WS_MASKJ + 1024 + tid * 4);
    mj1[0]=m4.x; mj1[1]=m4.y; mj1[2]=m4.z; mj1[3]=m4.w;
  }
  float cs[8] = {0,0,0,0,0,0,0,0};
  float rq0 = 0.f, rq1 = 0.f;
  float qy[7][2];
#pragma unroll
  for (int i = 0; i < 7; i++) { qy[i][0] = 0.f; qy[i][1] = 0.f; }

  for (int chunk = 0; chunk < 8; chunk++) {
    int n0 = blockIdx.x * 32 + chunk * 4;
    size_t cb = (size_t)(blockIdx.x * 8 + chunk) * 12800;
    __syncthreads();
    for (int r = 0; r < 4; r++) {
      const float* rowp = x0 + (size_t)(n0 + r) * VC;
      float4 xv = *(const float4*)(rowp + tid * 4);
      cs[0]+=xv.x; cs[1]+=xv.y; cs[2]+=xv.z; cs[3]+=xv.w;
      stage_elem(tid * 4, r, 4, xv, mj0, s_raw, s_xm);
      if (tid < 144) {
        float4 xw = *(const float4*)(rowp + 1024 + tid * 4);
        cs[4]+=xw.x; cs[5]+=xw.y; cs[6]+=xw.z; cs[7]+=xw.w;
        stage_elem(1024 + tid * 4, r, 4, xw, mj1, s_raw, s_xm);
      }
    }
    __syncthreads();
#pragma unroll
    for (int vp = 0; vp < 7; vp++) {
      int rb = vp * 16;
      const short* px = s_xm + (rb + l15) * 72 + quad * 8;
      const short* pr = s_raw + (rb + l15) * 72 + quad * 8;
      s16x8 a0 = *(const s16x8*)px;
      s16x8 a1 = *(const s16x8*)(px + 32);
      s16x8 r0 = *(const s16x8*)pr;
      s16x8 r1 = *(const s16x8*)(pr + 32);
#pragma unroll
      for (int a = 0; a < 2; a++) {
        f32x4 acc = {0.f, 0.f, 0.f, 0.f};
        acc = __builtin_amdgcn_mfma_f32_16x16x32_bf16(a0, bw[a][0], acc, 0, 0, 0);
        acc = __builtin_amdgcn_mfma_f32_16x16x32_bf16(a1, bw[a][1], acc, 0, 0, 0);
        qy[vp][a] += acc[0]*acc[0] + acc[1]*acc[1] + acc[2]*acc[2] + acc[3]*acc[3];
        f32x4 rc = {0.f, 0.f, 0.f, 0.f};
        rc = __builtin_amdgcn_mfma_f32_16x16x32_bf16(r0, bd[a][0], rc, 0, 0, 0);
        rc = __builtin_amdgcn_mfma_f32_16x16x32_bf16(r1, bd[a][1], rc, 0, 0, 0);
        float t2 = rc[0]*rc[0] + rc[1]*rc[1] + rc[2]*rc[2] + rc[3]*rc[3];
        if (a == 0) rq0 += t2; else rq1 += t2;
      }
      // transposed MFMAs (swap A/B): lane holds 4 consecutive d for one slot.
      // Fragment store: fully coalesced 512-B per wave instruction.
      if (do_store) {
#pragma unroll
        for (int aa = 0; aa < 2; aa++) {
          f32x4 tY = {0.f, 0.f, 0.f, 0.f};
          tY = __builtin_amdgcn_mfma_f32_16x16x32_bf16(bw[aa][0], a0, tY, 0, 0, 0);
          tY = __builtin_amdgcn_mfma_f32_16x16x32_bf16(bw[aa][1], a1, tY, 0, 0, 0);
          f32x4 tR = {0.f, 0.f, 0.f, 0.f};
          tR = __builtin_amdgcn_mfma_f32_16x16x32_bf16(bd[aa][0], r0, tR, 0, 0, 0);
          tR = __builtin_amdgcn_mfma_f32_16x16x32_bf16(bd[aa][1], r1, tR, 0, 0, 0);
          s16x4 ky, kr;
#pragma unroll
          for (int e = 0; e < 4; e++) { ky[e] = f2bf(tY[e]); kr[e] = f2bf(tR[e]); }
          if (vp < 6) {
            int off = vp * 2048 + wave * 512 + aa * 256 + lane * 4;
            *(s16x4*)(wsy + cb + off) = ky;
            *(s16x4*)(wsr + cb + off) = kr;
          } else if (l15 < 4) {
            int off = 12288 + (wave * 2 + aa) * 64 + (quad * 4 + l15) * 4;
            *(s16x4*)(wsy + cb + off) = ky;
            *(s16x4*)(wsr + cb + off) = kr;
          }
        }
      }
    }
  }
  // write partials straight from registers
  float* qp = ws + WS_QYP + (size_t)blockIdx.x * QYP_STRIDE;
  rq0 += __shfl_xor(rq0, 16); rq0 += __shfl_xor(rq0, 32);
  rq1 += __shfl_xor(rq1, 16); rq1 += __shfl_xor(rq1, 32);
  if (quad == 0) {
    qp[3200 + nt0 * 16 + l15] = rq0;
    qp[3200 + (nt0 + 1) * 16 + l15] = rq1;
  }
#pragma unroll
  for (int vp = 0; vp < 7; vp++) {
    int vq = vp * 4 + quad;
    if (vq < 25) {
      qp[vq * 128 + nt0 * 16 + l15] = qy[vp][0];
      qp[vq * 128 + (nt0 + 1) * 16 + l15] = qy[vp][1];
    }
  }
#pragma unroll
  for (int e = 0; e < 4; e++) atomicAdd(ws + WS_COLSUM + tid * 4 + e, cs[e]);
  if (tid < 144) {
#pragma unroll
    for (int e = 0; e < 4; e++) atomicAdd(ws + WS_COLSUM + 1024 + tid * 4 + e, cs[4 + e]);
  }
}

// ---------------- reduce ----------------
__global__ void k_reduce(const float* __restrict__ gamma, const float* __restrict__ beta,
                         const float* __restrict__ dgamma, const float* __restrict__ dbeta,
                         const float* __restrict__ W, const float* __restrict__ dw,
                         float* __restrict__ ws, int do_store) {
  int tid = threadIdx.x;
  if (blockIdx.x == 25) {
    __shared__ float s_cs[64];
    if (tid < 64) {
      float s = 0.f;
#pragma unroll
      for (int v = 0; v < 25; v++) s += ws[WS_COLSUM + v * 64 + tid];
      s_cs[tid] = s;
    }
    __syncthreads();
    int d = tid;
    float q = 0.f;
#pragma unroll 8
    for (int b2 = 0; b2 < 512; b2++) q += ws[WS_QYP + (size_t)b2 * QYP_STRIDE + 3200 + d];
    float m = 0.f;
#pragma unroll 8
    for (int c = 0; c < 64; c++) m += s_cs[c] * dw[d * 64 + c];
    m *= (1.0f / 409600.0f);
    float var = q * (1.0f / 409600.0f) - m * m;
    float a = dgamma[d] * rsqrtf(var + EPSF);
    ((float2*)(ws + WS_ABR))[d] = make_float2(a, dbeta[d] - m * a);
    return;
  }
  __shared__ float s_cm[1600];
  for (int t = tid; t < 1600; t += 128)
    s_cm[t] = ws[WS_COLSUM + t] * ws[WS_MASKJ + t];
  __syncthreads();
  int f = blockIdx.x * 128 + tid;
  int v = f >> 7, d = f & 127;
  float q = 0.f;
#pragma unroll 8
  for (int b2 = 0; b2 < 512; b2++) q += ws[WS_QYP + (size_t)b2 * QYP_STRIDE + f];
  float m = 0.f;
  int p = v * 64;
#pragma unroll 8
  for (int c = 0; c < 64; c++) {
    m += s_cm[p] * W[c * 128 + d];
    p += 65; if (p >= VC) p -= VC;
  }
  m *= (1.0f / 16384.0f);
  float var = q * (1.0f / 16384.0f) - m * m;
  int d25 = d % 25;
  int vo = v + d25; if (vo >= 25) vo -= 25;
  int jg = vo * 128 + d;
  float a = gamma[jg] * rsqrtf(var + EPSF);
  float bb = beta[jg] - m * a;
  ((float2*)(ws + WS_ABY))[f] = make_float2(a, bb);
  if (do_store) ((float2*)(ws + WS_ABY2))[vo * 128 + d] = make_float2(a, bb);
}

// ---------------- pass 2: linear fragment read -> LDS unscramble -> fused output ----------------
__launch_bounds__(256, 3)
__global__ void k_out(const float* __restrict__ ws, float* __restrict__ out) {
  __shared__ short s_y[12800];
  __shared__ short s_r[12800];
  int tid = threadIdx.x;
  int bid = blockIdx.x;
  const short* wsy = (const short*)ws + WS_Y_SH + (size_t)bid * 12800;
  const short* wsr = (const short*)ws + WS_R_SH + (size_t)bid * 12800;
  // stage: perfectly linear global reads; decode fragment -> (slot,d) -> swizzled LDS.
  for (int t = tid; t < 3200; t += 256) {
    int arr = (t >= 1600);
    int tt = arr ? (t - 1600) : t;
    const short* src = arr ? wsr : wsy;
    short* dst = arr ? s_r : s_y;
    s16x8 w = *(const s16x8*)(src + tt * 8);
#pragma unroll
    for (int h = 0; h < 2; h++) {
      int g = tt * 2 + h;
      int slot, d0;
      if (g < 3072) {
        int vp = g >> 9, rem = g & 511;
        int wv = rem >> 7, rem2 = rem & 127;
        int aa = rem2 >> 6, ln = rem2 & 63;
        slot = vp * 16 + (ln & 15);
        d0 = (wv * 2 + aa) * 16 + (ln >> 4) * 4;
      } else {
        int g2 = g - 3072;
        int cr = g2 >> 4, ci = g2 & 15;
        slot = 96 + (ci & 3);
        d0 = cr * 16 + (ci >> 2) * 4;
      }
      int v = slot >> 2, r = slot & 3;
      int L = r * 25 + v;
      int phys = ((L << 4) + ((d0 >> 3) ^ ((L * 5) & 15))) * 8 + (d0 & 7);
      s16x4 hh; hh[0] = w[h*4]; hh[1] = w[h*4+1]; hh[2] = w[h*4+2]; hh[3] = w[h*4+3];
      *(s16x4*)(dst + phys) = hh;
    }
  }
  __syncthreads();
  int n0 = bid * 4;
  int b = n0 >> 9, t0 = n0 & 511;
  float* ob = out + (size_t)b * 1638400 + (size_t)t0 * 25;
  const float2* aby2 = (const float2*)(ws + WS_ABY2);
  const float2* abrp = (const float2*)(ws + WS_ABR);
  for (int it = tid; it < 3200; it += 256) {
    int dd = it / 25;
    int qg = it - dd * 25;
    int q0 = qg * 4;
    int d25 = dd % 25;
    float2 ar = abrp[dd];
    int tl = q0 / 25;
    int vo = q0 - tl * 25;
    int sh = dd >> 3, dlo = dd & 7;
    float ov[4];
#pragma unroll
    for (int e = 0; e < 4; e++) {
      int vi = vo - d25; if (vi < 0) vi += 25;
      int Ly = tl * 25 + vi, Lr = tl * 25 + vo;
      int ady = ((Ly << 4) + (sh ^ ((Ly * 5) & 15))) * 8 + dlo;   // y is shift-scattered
      int adr = ((Lr << 4) + (sh ^ ((Lr * 5) & 15))) * 8 + dlo;   // res is not
      float yv = bf2f(s_y[ady]);
      float rv = bf2f(s_r[adr]);
      float2 ay = aby2[vo * 128 + dd];
      ov[e] = fmaxf(yv * ay.x + ay.y + rv * ar.x + ar.y, 0.0f);
      vo++; if (vo == 25) { vo = 0; tl++; }
    }
    float4 o; o.x = ov[0]; o.y = ov[1]; o.z = ov[2]; o.w = ov[3];
    *(float4*)(ob + (size_t)dd * 12800 + q0) = o;
  }
}

// ---------------- fallback pass 2 (small ws): original recompute kernel ----------------
__launch_bounds__(256, 2)
__global__ void k_main(const float* __restrict__ x0, const float* __restrict__ ws,
                       float* __restrict__ out) {
  __shared__ short s_raw[112 * 72];
  __shared__ short s_xm[112 * 72];
  __shared__ short s_ybuf[100 * 129];
  int tid = threadIdx.x;
  int wave = tid >> 6, lane = tid & 63, quad = lane >> 4, l15 = lane & 15;
  int n0 = blockIdx.x * 4;
  for (int t = tid; t < 1600; t += 256) {
    int flat = t * 4;
    int nl = flat / VC;
    int j = flat - nl * VC;
    float4 xv = *(const float4*)(x0 + (size_t)n0 * VC + flat);
    float4 m4 = *(const float4*)(ws + WS_MASKJ + j);
    float mj[4] = {m4.x, m4.y, m4.z, m4.w};
    stage_elem(j, nl * 25, 1, xv, mj, (short*)s_raw, (short*)s_xm);
  }
  __syncthreads();
  const s16x8* wpack = (const s16x8*)(ws + WS_WPACK);
  const float2* aby = (const float2*)(ws + WS_ABY);
  {
    s16x8 b0, b1;
#pragma unroll
    for (int ji = 0; ji < 14; ji++) {
      int job = wave * 14 + ji;
      int nt = job / 7, mt = job - nt * 7;
      if (ji == 0 || ji == 7) {
        b0 = wpack[(nt * 2 + 0) * 64 + lane];
        b1 = wpack[(nt * 2 + 1) * 64 + lane];
      }
      int mbase = mt * 16;
      const short* pa = s_xm + (mbase + l15) * 72 + quad * 8;
      s16x8 a0 = *(const s16x8*)(pa);
      s16x8 a1 = *(const s16x8*)(pa + 32);
      f32x4 acc = {0.f, 0.f, 0.f, 0.f};
      acc = __builtin_amdgcn_mfma_f32_16x16x32_bf16(a0, b0, acc, 0, 0, 0);
      acc = __builtin_amdgcn_mfma_f32_16x16x32_bf16(a1, b1, acc, 0, 0, 0);
      int d = nt * 16 + l15;
      int d25 = d % 25;
#pragma unroll
      for (int i = 0; i < 4; i++) {
        int s = mbase + quad * 4 + i;
        if (s < 100) {
          int r = s / 25;
          int vv = s - r * 25;
          float2 ab = aby[vv * 128 + d];
          float val = acc[i] * ab.x + ab.y;
          int vo = vv + d25; if (vo >= 25) vo -= 25;
          s_ybuf[(r * 25 + vo) * 129 + d] = f2bf(val);
        }
      }
    }
  }
  __syncthreads();
  const s16x8* dwpack = (const s16x8*)(ws + WS_DWPACK);
  const float2* abr = (const float2*)(ws + WS_ABR);
  {
    s16x8 b0, b1; float2 ab = make_float2(0.f, 0.f);
#pragma unroll
    for (int ji = 0; ji < 14; ji++) {
      int job = wave * 14 + ji;
      int nt = job / 7, mt = job - nt * 7;
      if (ji == 0 || ji == 7) {
        b0 = dwpack[(nt * 2 + 0) * 64 + lane];
        b1 = dwpack[(nt * 2 + 1) * 64 + lane];
        ab = abr[nt * 16 + l15];
      }
      int mbase = mt * 16;
      const short* pa = s_raw + (mbase + l15) * 72 + quad * 8;
      s16x8 a0 = *(const s16x8*)(pa);
      s16x8 a1 = *(const s16x8*)(pa + 32);
      f32x4 acc = {0.f, 0.f, 0.f, 0.f};
      acc = __builtin_amdgcn_mfma_f32_16x16x32_bf16(a0, b0, acc, 0, 0, 0);
      acc = __builtin_amdgcn_mfma_f32_16x16x32_bf16(a1, b1, acc, 0, 0, 0);
      int d = nt * 16 + l15;
#pragma unroll
      for (int i = 0; i < 4; i++) {
        int s = mbase + quad * 4 + i;
        if (s < 100) {
          int r = s / 25;
          int vv = s - r * 25;
          int ad = (r * 25 + vv) * 129 + d;
          float val = acc[i] * ab.x + ab.y + bf2f(s_ybuf[ad]);
          val = fmaxf(val, 0.0f);
          s_ybuf[ad] = f2bf(val);
        }
      }
    }
  }
  __syncthreads();
  int b = n0 >> 9, t0 = n0 & 511;
  float* ob = out + (size_t)b * 1638400 + (size_t)t0 * 25;
  for (int it = tid; it < 3200; it += 256) {
    int dd = it / 25;
    int qg = it - dd * 25;
    int q0 = qg * 4;
    float4 o;
    o.x = bf2f(s_ybuf[(q0 + 0) * 129 + dd]);
    o.y = bf2f(s_ybuf[(q0 + 1) * 129 + dd]);
    o.z = bf2f(s_ybuf[(q0 + 2) * 129 + dd]);
    o.w = bf2f(s_ybuf[(q0 + 3) * 129 + dd]);
    *(float4*)(ob + (size_t)dd * 12800 + q0) = o;
  }
}

extern "C" void kernel_launch(void* const* d_in, const int* in_sizes, int n_in,
                              void* d_out, int out_size, void* d_ws, size_t ws_size,
                              hipStream_t stream) {
  const float* x0    = (const float*)d_in[0];
  const float* fm    = (const float*)d_in[1];
  const float* W     = (const float*)d_in[2];
  const float* bn_g  = (const float*)d_in[4];
  const float* bn_b  = (const float*)d_in[5];
  const float* dw    = (const float*)d_in[6];
  const float* dbn_g = (const float*)d_in[8];
  const float* dbn_b = (const float*)d_in[9];
  float* ws = (float*)d_ws;
  float* out = (float*)d_out;
  int big = (ws_size >= WS_NEED_BYTES) ? 1 : 0;
  k_init<<<20, 256, 0, stream>>>(fm, W, dw, ws);
  k_stats<<<512, 256, 0, stream>>>(x0, ws, big);
  k_reduce<<<26, 128, 0, stream>>>(bn_g, bn_b, dbn_g, dbn_b, W, dw, ws, big);
  if (big) k_out<<<4096, 256, 0, stream>>>(ws, out);
  else     k_main<<<4096, 256, 0, stream>>>(x0, ws, out);
}

// Round 4
// 564.733 us; speedup vs baseline: 1.3141x; 1.2845x over previous
//
#include <hip/hip_runtime.h>

#define VC 1600
#define EPSF 1e-5f

// ws layout (float offsets)
#define WS_MASKJ  0
#define WS_WPACK  1600
#define WS_DWPACK 5696
#define WS_ABY    9792
#define WS_ABR    16192
#define WS_COLSUM 16448
#define WS_QY     18048            // 3328 floats: [0,3200)=y (v,d) sumsq, [3200,3328)=res d sumsq
// big-ws path regions
#define WS_ABY2   1721984          // float offset; 3200 float2 (dest-indexed coeffs)
#define WS_Y_SH   3456768          // SHORT offset: y bf16 fragment layout, 12800 shorts/chunk
#define WS_R_SH   55885568         // SHORT offset: res bf16 fragment layout
#define WS_NEED_BYTES 216628736ULL

typedef __attribute__((ext_vector_type(8))) short s16x8;
typedef __attribute__((ext_vector_type(4))) short s16x4;
typedef __attribute__((ext_vector_type(4))) float f32x4;

__device__ __forceinline__ short f2bf(float f) {
  unsigned u = __builtin_bit_cast(unsigned, f);
  u += 0x7fffu + ((u >> 16) & 1u);
  return (short)(u >> 16);
}
__device__ __forceinline__ float bf2f(short s) {
  unsigned u = ((unsigned)(unsigned short)s) << 16;
  return __builtin_bit_cast(float, u);
}

// stage one float4: raw (contiguous) + masked scatter to gathered position.
__device__ __forceinline__ void stage_elem(int j, int base, int vstr, float4 xv,
                                           const float* mj, short* s_raw, short* s_xm) {
  int u = j >> 6, c = j & 63;
  s16x4 pk; pk[0]=f2bf(xv.x); pk[1]=f2bf(xv.y); pk[2]=f2bf(xv.z); pk[3]=f2bf(xv.w);
  *(s16x4*)(s_raw + (base + u*vstr)*72 + c) = pk;
  int v0 = (u - c + 75) % 25;
  float xa[4] = {xv.x, xv.y, xv.z, xv.w};
#pragma unroll
  for (int e = 0; e < 4; e++) {
    int ve = v0 - e; if (ve < 0) ve += 25;
    s_xm[(base + ve*vstr)*72 + c + e] = f2bf(xa[e] * mj[e]);
  }
}

// ---------------- init ----------------
__global__ void k_init(const float* __restrict__ fm, const float* __restrict__ W,
                       const float* __restrict__ dw, float* __restrict__ ws) {
  int g = blockIdx.x * 256 + threadIdx.x;
  if (g < VC) {
    int c = g & 63, jv = g >> 6;
    int v = (jv - c + 75) % 25;
    ws[WS_MASKJ + g] = tanhf(fm[v * 64 + c]) + 1.0f;
    ws[WS_COLSUM + g] = 0.0f;
  }
  if (g < 3328) ws[WS_QY + g] = 0.0f;
  if (g >= 4096 && g < 5120) {
    int idx = g - 4096;
    int frag = idx >> 6, lane = idx & 63;
    int nt = frag >> 1, k = frag & 1, q = lane >> 4, l = lane & 15;
    s16x8 pk;
#pragma unroll
    for (int j = 0; j < 8; j++) {
      int c = k * 32 + q * 8 + j;
      pk[j] = f2bf(W[c * 128 + nt * 16 + l]);
    }
    ((s16x8*)(ws + WS_WPACK))[idx] = pk;
  }
  if (g >= 3328 && g < 4096) {
    // nothing
  }
  if (g >= 5120 - 1024 && g < 5120 && false) {}
  if (blockIdx.x >= 16) {
    int idx = (blockIdx.x - 16) * 256 + threadIdx.x;
    if (idx < 1024) {
      int frag = idx >> 6, lane = idx & 63;
      int nt = frag >> 1, k = frag & 1, q = lane >> 4, l = lane & 15;
      s16x8 pk;
#pragma unroll
      for (int j = 0; j < 8; j++) {
        int c = k * 32 + q * 8 + j;
        pk[j] = f2bf(dw[(nt * 16 + l) * 64 + c]);
      }
      ((s16x8*)(ws + WS_DWPACK))[idx] = pk;
    }
  }
}

// ---------------- pass 1: stats in regs (atomics at end) + fragment-layout y/res stores --------
// 4-row chunks (vstr=4): slot = r + v*4, 100 slots + 12 pad -> 7 MFMA tiles of 16.
// Fragment store: per (vp, wave, aa): 64 lanes x 8B contiguous = one 512-B line set.
// Chunk region (shorts): vp<6: vp*2048 + wave*512 + aa*256 + lane*4
//                        vp=6 (l15<4 only): 12288 + (wave*2+aa)*64 + (quad*4+l15)*4
__launch_bounds__(256, 2)
__global__ void k_stats(const float* __restrict__ x0, float* __restrict__ ws, int do_store) {
  __shared__ short s_raw[8064];   // 112 slots x 72
  __shared__ short s_xm[8064];
  int tid = threadIdx.x;
  int wave = tid >> 6, lane = tid & 63, quad = lane >> 4, l15 = lane & 15;
  for (int t = tid; t < 864; t += 256) { s_raw[7200 + t] = 0; s_xm[7200 + t] = 0; }
  const s16x8* wpack = (const s16x8*)(ws + WS_WPACK);
  const s16x8* dwpack = (const s16x8*)(ws + WS_DWPACK);
  short* wsy = (short*)ws + WS_Y_SH;
  short* wsr = (short*)ws + WS_R_SH;

  int nt0 = wave * 2;
  s16x8 bw[2][2], bd[2][2];
#pragma unroll
  for (int a = 0; a < 2; a++) {
    int nt = nt0 + a;
    bw[a][0] = wpack[(nt * 2 + 0) * 64 + lane];
    bw[a][1] = wpack[(nt * 2 + 1) * 64 + lane];
    bd[a][0] = dwpack[(nt * 2 + 0) * 64 + lane];
    bd[a][1] = dwpack[(nt * 2 + 1) * 64 + lane];
  }
  float mj0[4], mj1[4];
  {
    float4 m4 = *(const float4*)(ws + WS_MASKJ + tid * 4);
    mj0[0]=m4.x; mj0[1]=m4.y; mj0[2]=m4.z; mj0[3]=m4.w;
  }
  if (tid < 144) {
    float4 m4 = *(const float4*)(ws + WS_MASKJ + 1024 + tid * 4);
    mj1[0]=m4.x; mj1[1]=m4.y; mj1[2]=m4.z; mj1[3]=m4.w;
  }
  float cs[8] = {0,0,0,0,0,0,0,0};
  float rq0 = 0.f, rq1 = 0.f;
  float qy[7][2];
#pragma unroll
  for (int i = 0; i < 7; i++) { qy[i][0] = 0.f; qy[i][1] = 0.f; }

  for (int chunk = 0; chunk < 8; chunk++) {
    int n0 = blockIdx.x * 32 + chunk * 4;
    size_t cb = (size_t)(blockIdx.x * 8 + chunk) * 12800;
    __syncthreads();
    for (int r = 0; r < 4; r++) {
      const float* rowp = x0 + (size_t)(n0 + r) * VC;
      float4 xv = *(const float4*)(rowp + tid * 4);
      cs[0]+=xv.x; cs[1]+=xv.y; cs[2]+=xv.z; cs[3]+=xv.w;
      stage_elem(tid * 4, r, 4, xv, mj0, s_raw, s_xm);
      if (tid < 144) {
        float4 xw = *(const float4*)(rowp + 1024 + tid * 4);
        cs[4]+=xw.x; cs[5]+=xw.y; cs[6]+=xw.z; cs[7]+=xw.w;
        stage_elem(1024 + tid * 4, r, 4, xw, mj1, s_raw, s_xm);
      }
    }
    __syncthreads();
#pragma unroll
    for (int vp = 0; vp < 7; vp++) {
      int rb = vp * 16;
      const short* px = s_xm + (rb + l15) * 72 + quad * 8;
      const short* pr = s_raw + (rb + l15) * 72 + quad * 8;
      s16x8 a0 = *(const s16x8*)px;
      s16x8 a1 = *(const s16x8*)(px + 32);
      s16x8 r0 = *(const s16x8*)pr;
      s16x8 r1 = *(const s16x8*)(pr + 32);
#pragma unroll
      for (int a = 0; a < 2; a++) {
        f32x4 acc = {0.f, 0.f, 0.f, 0.f};
        acc = __builtin_amdgcn_mfma_f32_16x16x32_bf16(a0, bw[a][0], acc, 0, 0, 0);
        acc = __builtin_amdgcn_mfma_f32_16x16x32_bf16(a1, bw[a][1], acc, 0, 0, 0);
        qy[vp][a] += acc[0]*acc[0] + acc[1]*acc[1] + acc[2]*acc[2] + acc[3]*acc[3];
        f32x4 rc = {0.f, 0.f, 0.f, 0.f};
        rc = __builtin_amdgcn_mfma_f32_16x16x32_bf16(r0, bd[a][0], rc, 0, 0, 0);
        rc = __builtin_amdgcn_mfma_f32_16x16x32_bf16(r1, bd[a][1], rc, 0, 0, 0);
        float t2 = rc[0]*rc[0] + rc[1]*rc[1] + rc[2]*rc[2] + rc[3]*rc[3];
        if (a == 0) rq0 += t2; else rq1 += t2;
      }
      // transposed MFMAs (swap A/B): lane holds 4 consecutive d for one slot.
      // Fragment store: fully coalesced 512-B per wave instruction.
      if (do_store) {
#pragma unroll
        for (int aa = 0; aa < 2; aa++) {
          f32x4 tY = {0.f, 0.f, 0.f, 0.f};
          tY = __builtin_amdgcn_mfma_f32_16x16x32_bf16(bw[aa][0], a0, tY, 0, 0, 0);
          tY = __builtin_amdgcn_mfma_f32_16x16x32_bf16(bw[aa][1], a1, tY, 0, 0, 0);
          f32x4 tR = {0.f, 0.f, 0.f, 0.f};
          tR = __builtin_amdgcn_mfma_f32_16x16x32_bf16(bd[aa][0], r0, tR, 0, 0, 0);
          tR = __builtin_amdgcn_mfma_f32_16x16x32_bf16(bd[aa][1], r1, tR, 0, 0, 0);
          s16x4 ky, kr;
#pragma unroll
          for (int e = 0; e < 4; e++) { ky[e] = f2bf(tY[e]); kr[e] = f2bf(tR[e]); }
          if (vp < 6) {
            int off = vp * 2048 + wave * 512 + aa * 256 + lane * 4;
            *(s16x4*)(wsy + cb + off) = ky;
            *(s16x4*)(wsr + cb + off) = kr;
          } else if (l15 < 4) {
            int off = 12288 + (wave * 2 + aa) * 64 + (quad * 4 + l15) * 4;
            *(s16x4*)(wsy + cb + off) = ky;
            *(s16x4*)(wsr + cb + off) = kr;
          }
        }
      }
    }
  }
  // accumulate stats straight into global accumulators (zeroed by k_init each launch)
  rq0 += __shfl_xor(rq0, 16); rq0 += __shfl_xor(rq0, 32);
  rq1 += __shfl_xor(rq1, 16); rq1 += __shfl_xor(rq1, 32);
  if (quad == 0) {
    atomicAdd(ws + WS_QY + 3200 + nt0 * 16 + l15, rq0);
    atomicAdd(ws + WS_QY + 3200 + (nt0 + 1) * 16 + l15, rq1);
  }
#pragma unroll
  for (int vp = 0; vp < 7; vp++) {
    int vq = vp * 4 + quad;
    if (vq < 25) {
      atomicAdd(ws + WS_QY + vq * 128 + nt0 * 16 + l15, qy[vp][0]);
      atomicAdd(ws + WS_QY + vq * 128 + (nt0 + 1) * 16 + l15, qy[vp][1]);
    }
  }
#pragma unroll
  for (int e = 0; e < 4; e++) atomicAdd(ws + WS_COLSUM + tid * 4 + e, cs[e]);
  if (tid < 144) {
#pragma unroll
    for (int e = 0; e < 4; e++) atomicAdd(ws + WS_COLSUM + 1024 + tid * 4 + e, cs[4 + e]);
  }
}

// ---------------- reduce (QY already summed; cheap now) ----------------
__global__ void k_reduce(const float* __restrict__ gamma, const float* __restrict__ beta,
                         const float* __restrict__ dgamma, const float* __restrict__ dbeta,
                         const float* __restrict__ W, const float* __restrict__ dw,
                         float* __restrict__ ws, int do_store) {
  int tid = threadIdx.x;
  if (blockIdx.x == 25) {
    __shared__ float s_cs[64];
    if (tid < 64) {
      float s = 0.f;
#pragma unroll
      for (int v = 0; v < 25; v++) s += ws[WS_COLSUM + v * 64 + tid];
      s_cs[tid] = s;
    }
    __syncthreads();
    if (tid >= 128) return;
    int d = tid;
    float q = ws[WS_QY + 3200 + d];
    float m = 0.f;
#pragma unroll 8
    for (int c = 0; c < 64; c++) m += s_cs[c] * dw[d * 64 + c];
    m *= (1.0f / 409600.0f);
    float var = q * (1.0f / 409600.0f) - m * m;
    float a = dgamma[d] * rsqrtf(var + EPSF);
    ((float2*)(ws + WS_ABR))[d] = make_float2(a, dbeta[d] - m * a);
    return;
  }
  __shared__ float s_cm[1600];
  for (int t = tid; t < 1600; t += 128)
    s_cm[t] = ws[WS_COLSUM + t] * ws[WS_MASKJ + t];
  __syncthreads();
  int f = blockIdx.x * 128 + tid;
  int v = f >> 7, d = f & 127;
  float q = ws[WS_QY + f];
  float m = 0.f;
  int p = v * 64;
#pragma unroll 8
  for (int c = 0; c < 64; c++) {
    m += s_cm[p] * W[c * 128 + d];
    p += 65; if (p >= VC) p -= VC;
  }
  m *= (1.0f / 16384.0f);
  float var = q * (1.0f / 16384.0f) - m * m;
  int d25 = d % 25;
  int vo = v + d25; if (vo >= 25) vo -= 25;
  int jg = vo * 128 + d;
  float a = gamma[jg] * rsqrtf(var + EPSF);
  float bb = beta[jg] - m * a;
  ((float2*)(ws + WS_ABY))[f] = make_float2(a, bb);
  if (do_store) ((float2*)(ws + WS_ABY2))[vo * 128 + d] = make_float2(a, bb);
}

// ---------------- pass 2: linear fragment read -> LDS unscramble -> fused output ----------------
__launch_bounds__(256, 3)
__global__ void k_out(const float* __restrict__ ws, float* __restrict__ out) {
  __shared__ short s_y[12800];
  __shared__ short s_r[12800];
  int tid = threadIdx.x;
  int bid = blockIdx.x;
  const short* wsy = (const short*)ws + WS_Y_SH + (size_t)bid * 12800;
  const short* wsr = (const short*)ws + WS_R_SH + (size_t)bid * 12800;
  // stage: perfectly linear global reads; decode fragment -> (slot,d) -> swizzled LDS.
  for (int t = tid; t < 3200; t += 256) {
    int arr = (t >= 1600);
    int tt = arr ? (t - 1600) : t;
    const short* src = arr ? wsr : wsy;
    short* dst = arr ? s_r : s_y;
    s16x8 w = *(const s16x8*)(src + tt * 8);
#pragma unroll
    for (int h = 0; h < 2; h++) {
      int g = tt * 2 + h;
      int slot, d0;
      if (g < 3072) {
        int vp = g >> 9, rem = g & 511;
        int wv = rem >> 7, rem2 = rem & 127;
        int aa = rem2 >> 6, ln = rem2 & 63;
        slot = vp * 16 + (ln & 15);
        d0 = (wv * 2 + aa) * 16 + (ln >> 4) * 4;
      } else {
        int g2 = g - 3072;
        int cr = g2 >> 4, ci = g2 & 15;
        slot = 96 + (ci & 3);
        d0 = cr * 16 + (ci >> 2) * 4;
      }
      int v = slot >> 2, r = slot & 3;
      int L = r * 25 + v;
      int phys = ((L << 4) + ((d0 >> 3) ^ ((L * 5) & 15))) * 8 + (d0 & 7);
      s16x4 hh; hh[0] = w[h*4]; hh[1] = w[h*4+1]; hh[2] = w[h*4+2]; hh[3] = w[h*4+3];
      *(s16x4*)(dst + phys) = hh;
    }
  }
  __syncthreads();
  int n0 = bid * 4;
  int b = n0 >> 9, t0 = n0 & 511;
  float* ob = out + (size_t)b * 1638400 + (size_t)t0 * 25;
  const float2* aby2 = (const float2*)(ws + WS_ABY2);
  const float2* abrp = (const float2*)(ws + WS_ABR);
  for (int it = tid; it < 3200; it += 256) {
    int dd = it / 25;
    int qg = it - dd * 25;
    int q0 = qg * 4;
    int d25 = dd % 25;
    float2 ar = abrp[dd];
    int tl = q0 / 25;
    int vo = q0 - tl * 25;
    int sh = dd >> 3, dlo = dd & 7;
    float ov[4];
#pragma unroll
    for (int e = 0; e < 4; e++) {
      int vi = vo - d25; if (vi < 0) vi += 25;
      int Ly = tl * 25 + vi, Lr = tl * 25 + vo;
      int ady = ((Ly << 4) + (sh ^ ((Ly * 5) & 15))) * 8 + dlo;   // y is shift-scattered
      int adr = ((Lr << 4) + (sh ^ ((Lr * 5) & 15))) * 8 + dlo;   // res is not
      float yv = bf2f(s_y[ady]);
      float rv = bf2f(s_r[adr]);
      float2 ay = aby2[vo * 128 + dd];
      ov[e] = fmaxf(yv * ay.x + ay.y + rv * ar.x + ar.y, 0.0f);
      vo++; if (vo == 25) { vo = 0; tl++; }
    }
    float4 o; o.x = ov[0]; o.y = ov[1]; o.z = ov[2]; o.w = ov[3];
    *(float4*)(ob + (size_t)dd * 12800 + q0) = o;
  }
}

// ---------------- fallback pass 2 (small ws): original recompute kernel ----------------
__launch_bounds__(256, 2)
__global__ void k_main(const float* __restrict__ x0, const float* __restrict__ ws,
                       float* __restrict__ out) {
  __shared__ short s_raw[112 * 72];
  __shared__ short s_xm[112 * 72];
  __shared__ short s_ybuf[100 * 129];
  int tid = threadIdx.x;
  int wave = tid >> 6, lane = tid & 63, quad = lane >> 4, l15 = lane & 15;
  int n0 = blockIdx.x * 4;
  for (int t = tid; t < 1600; t += 256) {
    int flat = t * 4;
    int nl = flat / VC;
    int j = flat - nl * VC;
    float4 xv = *(const float4*)(x0 + (size_t)n0 * VC + flat);
    float4 m4 = *(const float4*)(ws + WS_MASKJ + j);
    float mj[4] = {m4.x, m4.y, m4.z, m4.w};
    stage_elem(j, nl * 25, 1, xv, mj, (short*)s_raw, (short*)s_xm);
  }
  __syncthreads();
  const s16x8* wpack = (const s16x8*)(ws + WS_WPACK);
  const float2* aby = (const float2*)(ws + WS_ABY);
  {
    s16x8 b0, b1;
#pragma unroll
    for (int ji = 0; ji < 14; ji++) {
      int job = wave * 14 + ji;
      int nt = job / 7, mt = job - nt * 7;
      if (ji == 0 || ji == 7) {
        b0 = wpack[(nt * 2 + 0) * 64 + lane];
        b1 = wpack[(nt * 2 + 1) * 64 + lane];
      }
      int mbase = mt * 16;
      const short* pa = s_xm + (mbase + l15) * 72 + quad * 8;
      s16x8 a0 = *(const s16x8*)(pa);
      s16x8 a1 = *(const s16x8*)(pa + 32);
      f32x4 acc = {0.f, 0.f, 0.f, 0.f};
      acc = __builtin_amdgcn_mfma_f32_16x16x32_bf16(a0, b0, acc, 0, 0, 0);
      acc = __builtin_amdgcn_mfma_f32_16x16x32_bf16(a1, b1, acc, 0, 0, 0);
      int d = nt * 16 + l15;
      int d25 = d % 25;
#pragma unroll
      for (int i = 0; i < 4; i++) {
        int s = mbase + quad * 4 + i;
        if (s < 100) {
          int r = s / 25;
          int vv = s - r * 25;
          float2 ab = aby[vv * 128 + d];
          float val = acc[i] * ab.x + ab.y;
          int vo = vv + d25; if (vo >= 25) vo -= 25;
          s_ybuf[(r * 25 + vo) * 129 + d] = f2bf(val);
        }
      }
    }
  }
  __syncthreads();
  const s16x8* dwpack = (const s16x8*)(ws + WS_DWPACK);
  const float2* abr = (const float2*)(ws + WS_ABR);
  {
    s16x8 b0, b1; float2 ab = make_float2(0.f, 0.f);
#pragma unroll
    for (int ji = 0; ji < 14; ji++) {
      int job = wave * 14 + ji;
      int nt = job / 7, mt = job - nt * 7;
      if (ji == 0 || ji == 7) {
        b0 = dwpack[(nt * 2 + 0) * 64 + lane];
        b1 = dwpack[(nt * 2 + 1) * 64 + lane];
        ab = abr[nt * 16 + l15];
      }
      int mbase = mt * 16;
      const short* pa = s_raw + (mbase + l15) * 72 + quad * 8;
      s16x8 a0 = *(const s16x8*)(pa);
      s16x8 a1 = *(const s16x8*)(pa + 32);
      f32x4 acc = {0.f, 0.f, 0.f, 0.f};
      acc = __builtin_amdgcn_mfma_f32_16x16x32_bf16(a0, b0, acc, 0, 0, 0);
      acc = __builtin_amdgcn_mfma_f32_16x16x32_bf16(a1, b1, acc, 0, 0, 0);
      int d = nt * 16 + l15;
#pragma unroll
      for (int i = 0; i < 4; i++) {
        int s = mbase + quad * 4 + i;
        if (s < 100) {
          int r = s / 25;
          int vv = s - r * 25;
          int ad = (r * 25 + vv) * 129 + d;
          float val = acc[i] * ab.x + ab.y + bf2f(s_ybuf[ad]);
          val = fmaxf(val, 0.0f);
          s_ybuf[ad] = f2bf(val);
        }
      }
    }
  }
  __syncthreads();
  int b = n0 >> 9, t0 = n0 & 511;
  float* ob = out + (size_t)b * 1638400 + (size_t)t0 * 25;
  for (int it = tid; it < 3200; it += 256) {
    int dd = it / 25;
    int qg = it - dd * 25;
    int q0 = qg * 4;
    float4 o;
    o.x = bf2f(s_ybuf[(q0 + 0) * 129 + dd]);
    o.y = bf2f(s_ybuf[(q0 + 1) * 129 + dd]);
    o.z = bf2f(s_ybuf[(q0 + 2) * 129 + dd]);
    o.w = bf2f(s_ybuf[(q0 + 3) * 129 + dd]);
    *(float4*)(ob + (size_t)dd * 12800 + q0) = o;
  }
}

extern "C" void kernel_launch(void* const* d_in, const int* in_sizes, int n_in,
                              void* d_out, int out_size, void* d_ws, size_t ws_size,
                              hipStream_t stream) {
  const float* x0    = (const float*)d_in[0];
  const float* fm    = (const float*)d_in[1];
  const float* W     = (const float*)d_in[2];
  const float* bn_g  = (const float*)d_in[4];
  const float* bn_b  = (const float*)d_in[5];
  const float* dw    = (const float*)d_in[6];
  const float* dbn_g = (const float*)d_in[8];
  const float* dbn_b = (const float*)d_in[9];
  float* ws = (float*)d_ws;
  float* out = (float*)d_out;
  int big = (ws_size >= WS_NEED_BYTES) ? 1 : 0;
  k_init<<<20, 256, 0, stream>>>(fm, W, dw, ws);
  k_stats<<<512, 256, 0, stream>>>(x0, ws, big);
  k_reduce<<<26, 128, 0, stream>>>(bn_g, bn_b, dbn_g, dbn_b, W, dw, ws, big);
  if (big) k_out<<<4096, 256, 0, stream>>>(ws, out);
  else     k_main<<<4096, 256, 0, stream>>>(x0, ws, out);
}